// Round 9
// baseline (71.728 us; speedup 1.0000x reference)
//
#include <hip/hip_runtime.h>
#include <hip/hip_bf16.h>

// y = softmax_causal((x Wq^T)(x Wk^T)^T / 8) (x Wv^T)
// B=4, S=4096, D_EMBED=1024, D=64. fp32 in/out; bf16 MFMA compute.

typedef short s16x8 __attribute__((ext_vector_type(8)));
typedef float f32x4 __attribute__((ext_vector_type(4)));
typedef float f32x16 __attribute__((ext_vector_type(16)));
typedef unsigned u32x2 __attribute__((ext_vector_type(2)));
typedef union { unsigned u[4]; s16x8 v; } pfrag;

#define MFMA16(a, b, c) __builtin_amdgcn_mfma_f32_16x16x32_bf16(a, b, c, 0, 0, 0)
#define MFMA32(a, b, c) __builtin_amdgcn_mfma_f32_32x32x16_bf16(a, b, c, 0, 0, 0)

constexpr int SEQ = 4096;
constexpr int DE  = 1024;

__device__ __forceinline__ short f2bf(float f) {            // RNE fp32->bf16
    union { float f; unsigned u; } v; v.f = f;
    unsigned r = (v.u + 0x7FFFu + ((v.u >> 16) & 1u)) >> 16;
    return (short)r;
}
__device__ __forceinline__ unsigned fbits(float f) { union { float f; unsigned u; } v; v.f = f; return v.u; }
__device__ __forceinline__ float bitsf(unsigned u) { union { unsigned u; float f; } v; v.u = u; return v.f; }
__device__ __forceinline__ unsigned pk2(float a, float b) {  // 2xf32 -> packed bf16 (trunc)
    return (fbits(b) & 0xFFFF0000u) | (fbits(a) >> 16);
}

#define GLDS(gp, lp)                                                          \
    __builtin_amdgcn_global_load_lds(                                         \
        (const __attribute__((address_space(1))) unsigned int*)(gp),          \
        (__attribute__((address_space(3))) unsigned int*)(lp), 16, 0, 0)

// ---------------------------------------------------------------------------
// Kernel 0: W (fp32 [64][1024] x3) -> bf16 [192][1024]; 0.125*log2e folded in Wq.
__global__ __launch_bounds__(256) void k_convw(const float* __restrict__ Wq,
                                               const float* __restrict__ Wk,
                                               const float* __restrict__ Wv,
                                               short* __restrict__ Wb) {
    int i = (blockIdx.x * 256 + threadIdx.x) * 4;
    if (i >= 192 * 1024) return;
    int n = i >> 10, k = i & 1023;
    const float* src; float sc;
    if (n < 64)       { src = Wq + n * 1024;         sc = 0.18033688011112042f; }
    else if (n < 128) { src = Wk + (n - 64) * 1024;  sc = 1.0f; }
    else              { src = Wv + (n - 128) * 1024; sc = 1.0f; }
    float4 v = *(const float4*)(src + k);
    short4 o;
    o.x = f2bf(v.x * sc); o.y = f2bf(v.y * sc);
    o.z = f2bf(v.z * sc); o.w = f2bf(v.w * sc);
    *(short4*)(Wb + i) = o;
}

// ---------------------------------------------------------------------------
// Kernel 1: QKV projection (R5 version): BM=64, BN=192, BK=64, 8 waves,
// counted vmcnt(5), 256 blocks x 512 thr.
__global__ __launch_bounds__(512) void k_proj(const float* __restrict__ x,
                                              const short* __restrict__ Wb,
                                              short* __restrict__ Qs,
                                              short* __restrict__ Ks,
                                              short* __restrict__ Vt) {
    __shared__ __align__(16) char lds[2][40960];   // per buf: A 16KB | W 24KB
    const int tid  = threadIdx.x;
    const int lane = tid & 63;
    const int c = lane & 15, g = (lane >> 4) & 3;
    const int wv = tid >> 6;
    const int rg = wv & 3, nh = wv >> 2;
    const int n0 = nh * 96;
    const int m0 = blockIdx.x * 64;

    const int Ar  = tid >> 4;
    const int Acs = ((tid & 15) << 4) ^ ((Ar & 7) << 4);
    const char* aS0 = (const char*)x + (((size_t)(m0 + Ar)) << 12) + Acs;
    const char* aS1 = aS0 + ((size_t)32 << 12);
    const int Wr  = tid >> 3;
    const int Wcs = ((tid & 7) << 4) ^ ((Wr & 7) << 4);
    const char* wS0 = (const char*)Wb + (((size_t)Wr) << 11) + Wcs;
    const char* wS1 = wS0 + ((size_t)64 << 11);
    const char* wS2 = wS0 + ((size_t)128 << 11);

    char* db0 = &lds[0][0] + tid * 16;
    char* db1 = &lds[1][0] + tid * 16;

    const int arow = rg * 16 + c;
    const int swz  = (c & 7) << 4;
    const char* aR[2] = { &lds[0][0] + arow * 256, &lds[1][0] + arow * 256 };
    const char* wR[2][6];
#pragma unroll
    for (int nf = 0; nf < 6; nf++) {
        int wrow = n0 + nf * 16 + c;
        wR[0][nf] = &lds[0][0] + 16384 + wrow * 128;
        wR[1][nf] = &lds[1][0] + 16384 + wrow * 128;
    }

    f32x4 acc[6];
#pragma unroll
    for (int i = 0; i < 6; i++) acc[i] = (f32x4){0.f, 0.f, 0.f, 0.f};

#define PSTAGE(kk, db) {                                  \
        GLDS(aS0 + (kk) * 256, (db));                     \
        GLDS(aS1 + (kk) * 256, (db) + 8192);              \
        GLDS(wS0 + (kk) * 128, (db) + 16384);             \
        GLDS(wS1 + (kk) * 128, (db) + 24576);             \
        GLDS(wS2 + (kk) * 128, (db) + 32768); }

#define PCOMPUTE(bi) {                                                         \
        _Pragma("unroll")                                                      \
        for (int kc = 0; kc < 2; kc++) {                                       \
            float4 a0 = *(const float4*)(aR[bi] + ((kc*128 + g*32)      ^ swz)); \
            float4 a1 = *(const float4*)(aR[bi] + ((kc*128 + g*32 + 16) ^ swz)); \
            s16x8 a;                                                           \
            a[0]=f2bf(a0.x); a[1]=f2bf(a0.y); a[2]=f2bf(a0.z); a[3]=f2bf(a0.w); \
            a[4]=f2bf(a1.x); a[5]=f2bf(a1.y); a[6]=f2bf(a1.z); a[7]=f2bf(a1.w); \
            _Pragma("unroll")                                                  \
            for (int nf = 0; nf < 6; nf++) {                                   \
                s16x8 bfr = *(const s16x8*)(wR[bi][nf] + ((kc*64 + g*16) ^ swz)); \
                acc[nf] = MFMA16(a, bfr, acc[nf]);                             \
            }                                                                  \
        } }

    PSTAGE(0, db0);
    PSTAGE(1, db1);

    for (int kk = 0; kk < 15; kk++) {
        asm volatile("s_waitcnt vmcnt(5)" ::: "memory");
        __builtin_amdgcn_sched_barrier(0);
        __builtin_amdgcn_s_barrier();
        if (kk & 1) PCOMPUTE(1) else PCOMPUTE(0)
        asm volatile("s_waitcnt lgkmcnt(0)" ::: "memory");
        __builtin_amdgcn_sched_barrier(0);
        __builtin_amdgcn_s_barrier();
        if (kk < 14) { if (kk & 1) PSTAGE(kk + 2, db1) else PSTAGE(kk + 2, db0) }
    }
    asm volatile("s_waitcnt vmcnt(0)" ::: "memory");
    __builtin_amdgcn_sched_barrier(0);
    __builtin_amdgcn_s_barrier();
    PCOMPUTE(1)
#undef PSTAGE
#undef PCOMPUTE

#pragma unroll
    for (int nf = 0; nf < 6; nf++) {
        int col16 = n0 + nf * 16;
        if (col16 < 64) {
            int col = col16 + c;
#pragma unroll
            for (int r = 0; r < 4; r++)
                Qs[(size_t)(m0 + rg * 16 + g * 4 + r) * 64 + col] = f2bf(acc[nf][r]);
        } else if (col16 < 128) {
            int col = col16 - 64 + c;
#pragma unroll
            for (int r = 0; r < 4; r++)
                Ks[(size_t)(m0 + rg * 16 + g * 4 + r) * 64 + col] = f2bf(acc[nf][r]);
        } else {
            int d  = col16 - 128 + c;
            int mm = m0 + rg * 16 + g * 4;
            int bt = mm >> 12, s0 = mm & (SEQ - 1);
            short4 o;
            o.x = f2bf(acc[nf][0]); o.y = f2bf(acc[nf][1]);
            o.z = f2bf(acc[nf][2]); o.w = f2bf(acc[nf][3]);
            *(short4*)(Vt + ((size_t)(bt * 64 + d)) * SEQ + s0) = o;
        }
    }
}

// ---------------------------------------------------------------------------
// Softmax tree + rescale for one tile (declares its own temporaries).
#define SMTREE(sa, sb, m, ll, o0, o1) {                                        \
    float mx8[8];                                                              \
    _Pragma("unroll")                                                          \
    for (int i2 = 0; i2 < 8; i2++)                                             \
        mx8[i2] = fmaxf(fmaxf(sa[i2], sa[i2 + 8]), fmaxf(sb[i2], sb[i2 + 8])); \
    float tm_ = fmaxf(fmaxf(fmaxf(mx8[0], mx8[1]), fmaxf(mx8[2], mx8[3])),     \
                      fmaxf(fmaxf(mx8[4], mx8[5]), fmaxf(mx8[6], mx8[7])));    \
    u32x2 sw_ = __builtin_amdgcn_permlane32_swap(fbits(tm_), fbits(tm_), false, false); \
    tm_ = fmaxf(bitsf(sw_[0]), bitsf(sw_[1]));                                 \
    float mn_ = fmaxf(m, tm_);                                                 \
    float sc_ = __builtin_amdgcn_exp2f(m - mn_);                               \
    m = mn_;                                                                   \
    _Pragma("unroll")                                                          \
    for (int i2 = 0; i2 < 16; i2++) {                                          \
        sa[i2] = __builtin_amdgcn_exp2f(sa[i2] - mn_);                         \
        sb[i2] = __builtin_amdgcn_exp2f(sb[i2] - mn_);                         \
    }                                                                          \
    float s8_[8];                                                              \
    _Pragma("unroll")                                                          \
    for (int i2 = 0; i2 < 8; i2++)                                             \
        s8_[i2] = (sa[i2] + sa[i2 + 8]) + (sb[i2] + sb[i2 + 8]);               \
    float ss_ = ((s8_[0] + s8_[1]) + (s8_[2] + s8_[3]))                        \
              + ((s8_[4] + s8_[5]) + (s8_[6] + s8_[7]));                       \
    sw_ = __builtin_amdgcn_permlane32_swap(fbits(ss_), fbits(ss_), false, false); \
    ss_ = bitsf(sw_[0]) + bitsf(sw_[1]);                                       \
    ll = ll * sc_ + ss_;                                                       \
    o0 *= sc_; o1 *= sc_; }

// P (two f32x16) -> 4 bf16 B-frags via pack + permlane32_swap.
#define PACKPH(sa, sb, u0, u1, u2, u3) {                                       \
    unsigned A0 = pk2(sa[0], sa[1]),   B0 = pk2(sa[2], sa[3]);                 \
    unsigned A1 = pk2(sa[4], sa[5]),   B1 = pk2(sa[6], sa[7]);                 \
    unsigned A2 = pk2(sa[8], sa[9]),   B2 = pk2(sa[10], sa[11]);               \
    unsigned A3 = pk2(sa[12], sa[13]), B3 = pk2(sa[14], sa[15]);               \
    u32x2 r0_ = __builtin_amdgcn_permlane32_swap(A0, A1, false, false);        \
    u32x2 r1_ = __builtin_amdgcn_permlane32_swap(B0, B1, false, false);        \
    u32x2 r2_ = __builtin_amdgcn_permlane32_swap(A2, A3, false, false);        \
    u32x2 r3_ = __builtin_amdgcn_permlane32_swap(B2, B3, false, false);        \
    u0.u[0] = r0_[0]; u0.u[1] = r1_[0]; u0.u[2] = r0_[1]; u0.u[3] = r1_[1];    \
    u1.u[0] = r2_[0]; u1.u[1] = r3_[0]; u1.u[2] = r2_[1]; u1.u[3] = r3_[1];    \
    A0 = pk2(sb[0], sb[1]);   B0 = pk2(sb[2], sb[3]);                          \
    A1 = pk2(sb[4], sb[5]);   B1 = pk2(sb[6], sb[7]);                          \
    A2 = pk2(sb[8], sb[9]);   B2 = pk2(sb[10], sb[11]);                        \
    A3 = pk2(sb[12], sb[13]); B3 = pk2(sb[14], sb[15]);                        \
    r0_ = __builtin_amdgcn_permlane32_swap(A0, A1, false, false);              \
    r1_ = __builtin_amdgcn_permlane32_swap(B0, B1, false, false);              \
    r2_ = __builtin_amdgcn_permlane32_swap(A2, A3, false, false);              \
    r3_ = __builtin_amdgcn_permlane32_swap(B2, B3, false, false);              \
    u2.u[0] = r0_[0]; u2.u[1] = r1_[0]; u2.u[2] = r0_[1]; u2.u[3] = r1_[1];    \
    u3.u[0] = r2_[0]; u3.u[1] = r3_[0]; u3.u[2] = r2_[1]; u3.u[3] = r3_[1]; }

// Full guarded single-tile body (slow path, near-diagonal rounds).
#define PROCT(qf, q0t, endt, m, ll, o0, o1) {                                  \
    if (k0 < (endt)) {                                                         \
        f32x16 sa = {}, sb = {};                                               \
        _Pragma("unroll")                                                      \
        for (int dd = 0; dd < 4; dd++) {                                       \
            int ch = ((2 * dd + hi) ^ qs7) << 4;                               \
            s16x8 ka  = *(const s16x8*)(kl + q * 128 + ch);                    \
            s16x8 kb2 = *(const s16x8*)(kl + (32 + q) * 128 + ch);             \
            sa = MFMA32(ka,  qf[dd], sa);                                      \
            sb = MFMA32(kb2, qf[dd], sb);                                      \
        }                                                                      \
        if (k0 + 31 > (q0t)) {                                                 \
            _Pragma("unroll")                                                  \
            for (int rr = 0; rr < 16; rr++) {                                  \
                int kv = k0 + (rr & 3) + 8 * (rr >> 2) + 4 * hi;               \
                if (kv > (q0t) + q) sa[rr] = -3.0e38f;                         \
            }                                                                  \
        }                                                                      \
        if (k0 + 63 > (q0t)) {                                                 \
            _Pragma("unroll")                                                  \
            for (int rr = 0; rr < 16; rr++) {                                  \
                int kv = k0 + 32 + (rr & 3) + 8 * (rr >> 2) + 4 * hi;          \
                if (kv > (q0t) + q) sb[rr] = -3.0e38f;                         \
            }                                                                  \
        }                                                                      \
        SMTREE(sa, sb, m, ll, o0, o1);                                         \
        pfrag u0_, u1_, u2_, u3_;                                              \
        PACKPH(sa, sb, u0_, u1_, u2_, u3_);                                    \
        _Pragma("unroll")                                                      \
        for (int dd = 0; dd < 4; dd++) {                                       \
            int ch = ((2 * dd + hi) ^ qs7) << 4;                               \
            s16x8 va  = *(const s16x8*)(vl + q * 128 + ch);                    \
            s16x8 vb2 = *(const s16x8*)(vl + (32 + q) * 128 + ch);             \
            pfrag* uu = dd == 0 ? &u0_ : dd == 1 ? &u1_ : dd == 2 ? &u2_ : &u3_; \
            o0 = MFMA32(va,  uu->v, o0);                                       \
            o1 = MFMA32(vb2, uu->v, o1);                                       \
        }                                                                      \
    } }

// ---------------------------------------------------------------------------
// Kernel 2 (v4): dual q-tile per wave. Block = 4 waves over 256 q-rows
// (wave wv: tile A rows J*256+wv*32, tile B rows +128). One 64-kv slab/round
// staged cooperatively (dbuf, vmcnt(4)); K/V LDS frags loaded ONCE per round
// and reused by both tiles (8 ds_reads -> 32 MFMAs). Fast path (94% of
// rounds, k0+63<=q0A): straight-line interleaved A/B chains -> scheduler
// overlaps A's softmax VALU with B's MFMAs. Work unit = (bt, J, 512-kv seg):
// 288 blocks heavy-first; partials (O^T,M,L) per 32q sub-tile -> ws.
__global__ __launch_bounds__(256, 2) void k_attn(const short* __restrict__ Qs,
                                                 const short* __restrict__ Ks,
                                                 const short* __restrict__ Vt,
                                                 float* __restrict__ pws) {
    __shared__ __align__(16) char smem[2][16384];   // per buf: K 8KB | V 8KB

    int tid = threadIdx.x;
    int l = tid & 63, wv = tid >> 6;
    int q = l & 31, hi = l >> 5;

    // decode unit: heavy tiles (large J) first; nseg(J) = (J+2)>>1
    int ub = blockIdx.x >> 2, bt = blockIdx.x & 3;
    int u = ub, J = 15, cs = 8;
    while (u >= cs) { u -= cs; --J; cs = (J + 2) >> 1; }
    int seg = u;
    int kb0 = seg << 9;
    int kend_t = min(J * 256 + 256, kb0 + 512);
    const int R = (kend_t - kb0) >> 6;
    const int q0A = J * 256 + wv * 32;
    const int q0B = q0A + 128;
    const int endA = q0A + 32, endB = q0B + 32;

    const short* Qb = Qs + (size_t)bt * SEQ * 64;
    const short* Kb = Ks + (size_t)bt * SEQ * 64;
    const short* Vb = Vt + (size_t)bt * 64 * SEQ;

    s16x8 qfA[4], qfB[4];
#pragma unroll
    for (int d = 0; d < 4; d++) {
        qfA[d] = *(const s16x8*)(Qb + (size_t)(q0A + q) * 64 + d * 16 + hi * 8);
        qfB[d] = *(const s16x8*)(Qb + (size_t)(q0B + q) * 64 + d * 16 + hi * 8);
    }

    const int row8 = l >> 3;
    const int scs  = (l & 7) ^ row8;       // pre-XORed source chunk

#define ASTAGE(kb, b) {                                                        \
        _Pragma("unroll")                                                      \
        for (int i = 0; i < 2; i++) {                                          \
            GLDS(Kb + (((size_t)((kb) + wv*16 + i*8 + row8)) << 6) + scs*8,    \
                 &smem[b][0] + (wv*16 + i*8)*128);                             \
            GLDS(Vb + (size_t)(wv*16 + i*8 + row8) * SEQ + (kb) + scs*8,       \
                 &smem[b][0] + 8192 + (wv*16 + i*8)*128); } }

    f32x16 oA0 = {}, oA1 = {}, oB0 = {}, oB1 = {};
    float mA = -1e30f, llA = 0.f, mB = -1e30f, llB = 0.f;
    const int qs7 = q & 7;

    ASTAGE(kb0, 0);
    if (R > 1) ASTAGE(kb0 + 64, 1);

    for (int r = 0; r < R; r++) {
        if (r == R - 1) asm volatile("s_waitcnt vmcnt(0)" ::: "memory");
        else            asm volatile("s_waitcnt vmcnt(4)" ::: "memory");
        __builtin_amdgcn_sched_barrier(0);
        __builtin_amdgcn_s_barrier();
        __builtin_amdgcn_sched_barrier(0);

        int k0 = kb0 + r * 64;
        const char* kl = &smem[r & 1][0];
        const char* vl = kl + 8192;

        if (k0 + 63 <= q0A) {
            // ---------- FAST PATH: both tiles, no masks, shared frags ----------
            s16x8 kf[8];
#pragma unroll
            for (int dd = 0; dd < 4; dd++) {
                int ch = ((2 * dd + hi) ^ qs7) << 4;
                kf[dd]     = *(const s16x8*)(kl + q * 128 + ch);
                kf[4 + dd] = *(const s16x8*)(kl + (32 + q) * 128 + ch);
            }
            f32x16 saA = {}, sbA = {}, saB = {}, sbB = {};
#pragma unroll
            for (int dd = 0; dd < 4; dd++) {
                saA = MFMA32(kf[dd],     qfA[dd], saA);
                sbA = MFMA32(kf[4 + dd], qfA[dd], sbA);
                saB = MFMA32(kf[dd],     qfB[dd], saB);
                sbB = MFMA32(kf[4 + dd], qfB[dd], sbB);
            }
            SMTREE(saA, sbA, mA, llA, oA0, oA1);
            pfrag uA0, uA1, uA2, uA3;
            PACKPH(saA, sbA, uA0, uA1, uA2, uA3);
            s16x8 vf[8];
#pragma unroll
            for (int dd = 0; dd < 4; dd++) {
                int ch = ((2 * dd + hi) ^ qs7) << 4;
                vf[dd]     = *(const s16x8*)(vl + q * 128 + ch);
                vf[4 + dd] = *(const s16x8*)(vl + (32 + q) * 128 + ch);
            }
            oA0 = MFMA32(vf[0], uA0.v, oA0);
            oA0 = MFMA32(vf[1], uA1.v, oA0);
            oA0 = MFMA32(vf[2], uA2.v, oA0);
            oA0 = MFMA32(vf[3], uA3.v, oA0);
            oA1 = MFMA32(vf[4], uA0.v, oA1);
            oA1 = MFMA32(vf[5], uA1.v, oA1);
            oA1 = MFMA32(vf[6], uA2.v, oA1);
            oA1 = MFMA32(vf[7], uA3.v, oA1);
            SMTREE(saB, sbB, mB, llB, oB0, oB1);
            pfrag uB0, uB1, uB2, uB3;
            PACKPH(saB, sbB, uB0, uB1, uB2, uB3);
            oB0 = MFMA32(vf[0], uB0.v, oB0);
            oB0 = MFMA32(vf[1], uB1.v, oB0);
            oB0 = MFMA32(vf[2], uB2.v, oB0);
            oB0 = MFMA32(vf[3], uB3.v, oB0);
            oB1 = MFMA32(vf[4], uB0.v, oB1);
            oB1 = MFMA32(vf[5], uB1.v, oB1);
            oB1 = MFMA32(vf[6], uB2.v, oB1);
            oB1 = MFMA32(vf[7], uB3.v, oB1);
        } else {
            // ---------- SLOW PATH: per-tile guarded + masked ----------
            PROCT(qfA, q0A, endA, mA, llA, oA0, oA1);
            PROCT(qfB, q0B, endB, mB, llB, oB0, oB1);
        }

        asm volatile("s_waitcnt lgkmcnt(0)" ::: "memory");
        __builtin_amdgcn_sched_barrier(0);
        __builtin_amdgcn_s_barrier();
        if (r + 2 < R) { if (r & 1) ASTAGE(kb0 + (r + 2) * 64, 1) else ASTAGE(kb0 + (r + 2) * 64, 0) }
    }
#undef ASTAGE

    // ---- partials: tile A -> sub=wv, tile B -> sub=4+wv ----
    {
        float* p = pws + ((size_t)(((bt * 16 + J) * 8 + wv) * 8 + seg)) * 2112;
#pragma unroll
        for (int rr = 0; rr < 16; rr++) {
            int dv = (rr & 3) + 8 * (rr >> 2) + 4 * hi;
            p[dv * 32 + q]        = oA0[rr];
            p[(dv + 32) * 32 + q] = oA1[rr];
        }
        if (hi == 0) { p[2048 + q] = mA; p[2080 + q] = llA; }
    }
    {
        float* p = pws + ((size_t)(((bt * 16 + J) * 8 + 4 + wv) * 8 + seg)) * 2112;
#pragma unroll
        for (int rr = 0; rr < 16; rr++) {
            int dv = (rr & 3) + 8 * (rr >> 2) + 4 * hi;
            p[dv * 32 + q]        = oB0[rr];
            p[(dv + 32) * 32 + q] = oB1[rr];
        }
        if (hi == 0) { p[2048 + q] = mB; p[2080 + q] = llB; }
    }
}

// ---------------------------------------------------------------------------
// Kernel 3: merge segment partials per (bt, J, sub) -> fp32 out. Grid 512.
__global__ __launch_bounds__(256) void k_comb(const float* __restrict__ pws,
                                              float* __restrict__ out) {
    int b = blockIdx.x;                      // ((bt*16+J)*8+sub)
    int sub = b & 7, J = (b >> 3) & 15, bt = b >> 7;
    int qbase = J * 256 + (sub >> 2) * 128 + (sub & 3) * 32;
    int nseg = (qbase + 32 + 511) >> 9;

    int tid = threadIdx.x;
    int q = tid >> 3, dv0 = (tid & 7) * 8;
    const float* base = pws + (size_t)b * 8 * 2112;

    float ms[8], wsg[8];
    float M = -1e30f;
#pragma unroll
    for (int s = 0; s < 8; s++) {
        if (s < nseg) { ms[s] = base[s * 2112 + 2048 + q]; M = fmaxf(M, ms[s]); }
    }
    float L = 0.f;
#pragma unroll
    for (int s = 0; s < 8; s++) {
        if (s < nseg) {
            wsg[s] = __builtin_amdgcn_exp2f(ms[s] - M);
            L += wsg[s] * base[s * 2112 + 2080 + q];
        }
    }
    float inv = 1.0f / L;
    float res[8];
#pragma unroll
    for (int i = 0; i < 8; i++) res[i] = 0.f;
#pragma unroll
    for (int s = 0; s < 8; s++) {
        if (s < nseg) {
            const float* po = base + s * 2112;
#pragma unroll
            for (int i = 0; i < 8; i++) res[i] += wsg[s] * po[(dv0 + i) * 32 + q];
        }
    }
    float* op = out + ((size_t)bt * SEQ + qbase + q) * 64 + dv0;
    float4 f0 = {res[0] * inv, res[1] * inv, res[2] * inv, res[3] * inv};
    float4 f1 = {res[4] * inv, res[5] * inv, res[6] * inv, res[7] * inv};
    *(float4*)op = f0;
    *(float4*)(op + 4) = f1;
}

// ---------------------------------------------------------------------------
extern "C" void kernel_launch(void* const* d_in, const int* in_sizes, int n_in,
                              void* d_out, int out_size, void* d_ws, size_t ws_size,
                              hipStream_t stream) {
    const float* x  = (const float*)d_in[0];
    const float* Wq = (const float*)d_in[1];
    const float* Wk = (const float*)d_in[2];
    const float* Wv = (const float*)d_in[3];
    float* out = (float*)d_out;

    char* ws = (char*)d_ws;
    short* Wb = (short*)ws;                                   // 384 KB
    short* Qs = (short*)(ws + 393216);                        // 2 MB
    short* Ks = (short*)(ws + 393216 + 2097152);              // 2 MB
    short* Vt = (short*)(ws + 393216 + 2 * 2097152);          // 2 MB  [B][64][S]
    float* pP = (float*)(ws + 6684672);                       // partials ~34.6 MB

    k_convw<<<dim3(192), dim3(256), 0, stream>>>(Wq, Wk, Wv, Wb);
    k_proj <<<dim3(256), dim3(512), 0, stream>>>(x, Wb, Qs, Ks, Vt);
    k_attn <<<dim3(288), dim3(256), 0, stream>>>(Qs, Ks, Vt, pP);
    k_comb <<<dim3(512), dim3(256), 0, stream>>>(pP, out);
}

// Round 10
// 68.425 us; speedup vs baseline: 1.0483x; 1.0483x over previous
//
#include <hip/hip_runtime.h>
#include <hip/hip_bf16.h>

// y = softmax_causal((x Wq^T)(x Wk^T)^T / 8) (x Wv^T)
// B=4, S=4096, D_EMBED=1024, D=64. fp32 in/out; bf16 MFMA compute.

typedef short s16x8 __attribute__((ext_vector_type(8)));
typedef float f32x4 __attribute__((ext_vector_type(4)));
typedef float f32x16 __attribute__((ext_vector_type(16)));
typedef unsigned u32x2 __attribute__((ext_vector_type(2)));
typedef union { unsigned u[4]; s16x8 v; } pfrag;

#define MFMA16(a, b, c) __builtin_amdgcn_mfma_f32_16x16x32_bf16(a, b, c, 0, 0, 0)
#define MFMA32(a, b, c) __builtin_amdgcn_mfma_f32_32x32x16_bf16(a, b, c, 0, 0, 0)

constexpr int SEQ = 4096;
constexpr int DE  = 1024;

__device__ __forceinline__ short f2bf(float f) {            // RNE fp32->bf16
    union { float f; unsigned u; } v; v.f = f;
    unsigned r = (v.u + 0x7FFFu + ((v.u >> 16) & 1u)) >> 16;
    return (short)r;
}
__device__ __forceinline__ unsigned fbits(float f) { union { float f; unsigned u; } v; v.f = f; return v.u; }
__device__ __forceinline__ float bitsf(unsigned u) { union { unsigned u; float f; } v; v.u = u; return v.f; }
__device__ __forceinline__ unsigned pk2(float a, float b) {  // 2xf32 -> packed bf16 (trunc)
    return (fbits(b) & 0xFFFF0000u) | (fbits(a) >> 16);
}

#define GLDS(gp, lp)                                                          \
    __builtin_amdgcn_global_load_lds(                                         \
        (const __attribute__((address_space(1))) unsigned int*)(gp),          \
        (__attribute__((address_space(3))) unsigned int*)(lp), 16, 0, 0)

// ---------------------------------------------------------------------------
// Kernel 0: W (fp32 [64][1024] x3) -> bf16 [192][1024]; 0.125*log2e folded in Wq.
__global__ __launch_bounds__(256) void k_convw(const float* __restrict__ Wq,
                                               const float* __restrict__ Wk,
                                               const float* __restrict__ Wv,
                                               short* __restrict__ Wb) {
    int i = (blockIdx.x * 256 + threadIdx.x) * 4;
    if (i >= 192 * 1024) return;
    int n = i >> 10, k = i & 1023;
    const float* src; float sc;
    if (n < 64)       { src = Wq + n * 1024;         sc = 0.18033688011112042f; }
    else if (n < 128) { src = Wk + (n - 64) * 1024;  sc = 1.0f; }
    else              { src = Wv + (n - 128) * 1024; sc = 1.0f; }
    float4 v = *(const float4*)(src + k);
    short4 o;
    o.x = f2bf(v.x * sc); o.y = f2bf(v.y * sc);
    o.z = f2bf(v.z * sc); o.w = f2bf(v.w * sc);
    *(short4*)(Wb + i) = o;
}

// ---------------------------------------------------------------------------
// Kernel 1: QKV projection (R5 version): BM=64, BN=192, BK=64, 8 waves,
// counted vmcnt(5), 256 blocks x 512 thr.
__global__ __launch_bounds__(512) void k_proj(const float* __restrict__ x,
                                              const short* __restrict__ Wb,
                                              short* __restrict__ Qs,
                                              short* __restrict__ Ks,
                                              short* __restrict__ Vt) {
    __shared__ __align__(16) char lds[2][40960];   // per buf: A 16KB | W 24KB
    const int tid  = threadIdx.x;
    const int lane = tid & 63;
    const int c = lane & 15, g = (lane >> 4) & 3;
    const int wv = tid >> 6;
    const int rg = wv & 3, nh = wv >> 2;
    const int n0 = nh * 96;
    const int m0 = blockIdx.x * 64;

    const int Ar  = tid >> 4;
    const int Acs = ((tid & 15) << 4) ^ ((Ar & 7) << 4);
    const char* aS0 = (const char*)x + (((size_t)(m0 + Ar)) << 12) + Acs;
    const char* aS1 = aS0 + ((size_t)32 << 12);
    const int Wr  = tid >> 3;
    const int Wcs = ((tid & 7) << 4) ^ ((Wr & 7) << 4);
    const char* wS0 = (const char*)Wb + (((size_t)Wr) << 11) + Wcs;
    const char* wS1 = wS0 + ((size_t)64 << 11);
    const char* wS2 = wS0 + ((size_t)128 << 11);

    char* db0 = &lds[0][0] + tid * 16;
    char* db1 = &lds[1][0] + tid * 16;

    const int arow = rg * 16 + c;
    const int swz  = (c & 7) << 4;
    const char* aR[2] = { &lds[0][0] + arow * 256, &lds[1][0] + arow * 256 };
    const char* wR[2][6];
#pragma unroll
    for (int nf = 0; nf < 6; nf++) {
        int wrow = n0 + nf * 16 + c;
        wR[0][nf] = &lds[0][0] + 16384 + wrow * 128;
        wR[1][nf] = &lds[1][0] + 16384 + wrow * 128;
    }

    f32x4 acc[6];
#pragma unroll
    for (int i = 0; i < 6; i++) acc[i] = (f32x4){0.f, 0.f, 0.f, 0.f};

#define PSTAGE(kk, db) {                                  \
        GLDS(aS0 + (kk) * 256, (db));                     \
        GLDS(aS1 + (kk) * 256, (db) + 8192);              \
        GLDS(wS0 + (kk) * 128, (db) + 16384);             \
        GLDS(wS1 + (kk) * 128, (db) + 24576);             \
        GLDS(wS2 + (kk) * 128, (db) + 32768); }

#define PCOMPUTE(bi) {                                                         \
        _Pragma("unroll")                                                      \
        for (int kc = 0; kc < 2; kc++) {                                       \
            float4 a0 = *(const float4*)(aR[bi] + ((kc*128 + g*32)      ^ swz)); \
            float4 a1 = *(const float4*)(aR[bi] + ((kc*128 + g*32 + 16) ^ swz)); \
            s16x8 a;                                                           \
            a[0]=f2bf(a0.x); a[1]=f2bf(a0.y); a[2]=f2bf(a0.z); a[3]=f2bf(a0.w); \
            a[4]=f2bf(a1.x); a[5]=f2bf(a1.y); a[6]=f2bf(a1.z); a[7]=f2bf(a1.w); \
            _Pragma("unroll")                                                  \
            for (int nf = 0; nf < 6; nf++) {                                   \
                s16x8 bfr = *(const s16x8*)(wR[bi][nf] + ((kc*64 + g*16) ^ swz)); \
                acc[nf] = MFMA16(a, bfr, acc[nf]);                             \
            }                                                                  \
        } }

    PSTAGE(0, db0);
    PSTAGE(1, db1);

    for (int kk = 0; kk < 15; kk++) {
        asm volatile("s_waitcnt vmcnt(5)" ::: "memory");
        __builtin_amdgcn_sched_barrier(0);
        __builtin_amdgcn_s_barrier();
        if (kk & 1) PCOMPUTE(1) else PCOMPUTE(0)
        asm volatile("s_waitcnt lgkmcnt(0)" ::: "memory");
        __builtin_amdgcn_sched_barrier(0);
        __builtin_amdgcn_s_barrier();
        if (kk < 14) { if (kk & 1) PSTAGE(kk + 2, db1) else PSTAGE(kk + 2, db0) }
    }
    asm volatile("s_waitcnt vmcnt(0)" ::: "memory");
    __builtin_amdgcn_sched_barrier(0);
    __builtin_amdgcn_s_barrier();
    PCOMPUTE(1)
#undef PSTAGE
#undef PCOMPUTE

#pragma unroll
    for (int nf = 0; nf < 6; nf++) {
        int col16 = n0 + nf * 16;
        if (col16 < 64) {
            int col = col16 + c;
#pragma unroll
            for (int r = 0; r < 4; r++)
                Qs[(size_t)(m0 + rg * 16 + g * 4 + r) * 64 + col] = f2bf(acc[nf][r]);
        } else if (col16 < 128) {
            int col = col16 - 64 + c;
#pragma unroll
            for (int r = 0; r < 4; r++)
                Ks[(size_t)(m0 + rg * 16 + g * 4 + r) * 64 + col] = f2bf(acc[nf][r]);
        } else {
            int d  = col16 - 128 + c;
            int mm = m0 + rg * 16 + g * 4;
            int bt = mm >> 12, s0 = mm & (SEQ - 1);
            short4 o;
            o.x = f2bf(acc[nf][0]); o.y = f2bf(acc[nf][1]);
            o.z = f2bf(acc[nf][2]); o.w = f2bf(acc[nf][3]);
            *(short4*)(Vt + ((size_t)(bt * 64 + d)) * SEQ + s0) = o;
        }
    }
}

// ---------------------------------------------------------------------------
// Softmax tree + rescale for one tile.
#define SMTREE(sa, sb, m, ll, o0, o1) {                                        \
    float mx8[8];                                                              \
    _Pragma("unroll")                                                          \
    for (int i2 = 0; i2 < 8; i2++)                                             \
        mx8[i2] = fmaxf(fmaxf(sa[i2], sa[i2 + 8]), fmaxf(sb[i2], sb[i2 + 8])); \
    float tm_ = fmaxf(fmaxf(fmaxf(mx8[0], mx8[1]), fmaxf(mx8[2], mx8[3])),     \
                      fmaxf(fmaxf(mx8[4], mx8[5]), fmaxf(mx8[6], mx8[7])));    \
    u32x2 sw_ = __builtin_amdgcn_permlane32_swap(fbits(tm_), fbits(tm_), false, false); \
    tm_ = fmaxf(bitsf(sw_[0]), bitsf(sw_[1]));                                 \
    float mn_ = fmaxf(m, tm_);                                                 \
    float sc_ = __builtin_amdgcn_exp2f(m - mn_);                               \
    m = mn_;                                                                   \
    _Pragma("unroll")                                                          \
    for (int i2 = 0; i2 < 16; i2++) {                                          \
        sa[i2] = __builtin_amdgcn_exp2f(sa[i2] - mn_);                         \
        sb[i2] = __builtin_amdgcn_exp2f(sb[i2] - mn_);                         \
    }                                                                          \
    float s8_[8];                                                              \
    _Pragma("unroll")                                                          \
    for (int i2 = 0; i2 < 8; i2++)                                             \
        s8_[i2] = (sa[i2] + sa[i2 + 8]) + (sb[i2] + sb[i2 + 8]);               \
    float ss_ = ((s8_[0] + s8_[1]) + (s8_[2] + s8_[3]))                        \
              + ((s8_[4] + s8_[5]) + (s8_[6] + s8_[7]));                       \
    sw_ = __builtin_amdgcn_permlane32_swap(fbits(ss_), fbits(ss_), false, false); \
    ss_ = bitsf(sw_[0]) + bitsf(sw_[1]);                                       \
    ll = ll * sc_ + ss_;                                                       \
    o0 *= sc_; o1 *= sc_; }

// P (two f32x16) -> 4 bf16 B-frags via pack + permlane32_swap.
#define PACKPH(sa, sb, u0, u1, u2, u3) {                                       \
    unsigned A0 = pk2(sa[0], sa[1]),   B0 = pk2(sa[2], sa[3]);                 \
    unsigned A1 = pk2(sa[4], sa[5]),   B1 = pk2(sa[6], sa[7]);                 \
    unsigned A2 = pk2(sa[8], sa[9]),   B2 = pk2(sa[10], sa[11]);               \
    unsigned A3 = pk2(sa[12], sa[13]), B3 = pk2(sa[14], sa[15]);               \
    u32x2 r0_ = __builtin_amdgcn_permlane32_swap(A0, A1, false, false);        \
    u32x2 r1_ = __builtin_amdgcn_permlane32_swap(B0, B1, false, false);        \
    u32x2 r2_ = __builtin_amdgcn_permlane32_swap(A2, A3, false, false);        \
    u32x2 r3_ = __builtin_amdgcn_permlane32_swap(B2, B3, false, false);        \
    u0.u[0] = r0_[0]; u0.u[1] = r1_[0]; u0.u[2] = r0_[1]; u0.u[3] = r1_[1];    \
    u1.u[0] = r2_[0]; u1.u[1] = r3_[0]; u1.u[2] = r2_[1]; u1.u[3] = r3_[1];    \
    A0 = pk2(sb[0], sb[1]);   B0 = pk2(sb[2], sb[3]);                          \
    A1 = pk2(sb[4], sb[5]);   B1 = pk2(sb[6], sb[7]);                          \
    A2 = pk2(sb[8], sb[9]);   B2 = pk2(sb[10], sb[11]);                        \
    A3 = pk2(sb[12], sb[13]); B3 = pk2(sb[14], sb[15]);                        \
    r0_ = __builtin_amdgcn_permlane32_swap(A0, A1, false, false);              \
    r1_ = __builtin_amdgcn_permlane32_swap(B0, B1, false, false);              \
    r2_ = __builtin_amdgcn_permlane32_swap(A2, A3, false, false);              \
    r3_ = __builtin_amdgcn_permlane32_swap(B2, B3, false, false);              \
    u2.u[0] = r0_[0]; u2.u[1] = r1_[0]; u2.u[2] = r0_[1]; u2.u[3] = r1_[1];    \
    u3.u[0] = r2_[0]; u3.u[1] = r3_[0]; u3.u[2] = r2_[1]; u3.u[3] = r3_[1]; }

// ---------------------------------------------------------------------------
// Kernel 2 (v5): barrier-minimal round. The barrier-bracketed region contains
// ONLY the 16 ds_read_b128 (K,V frags -> regs); all compute (QK, softmax,
// pack, PV) runs barrier-free from registers, so rounds/waves/blocks overlap.
//   round: vmcnt(N); bar; ds_read x16; lgkmcnt(0); bar; STAGE(r+2); compute
// Units = (bt, 128q-tile j, 512-kv seg): 576 blocks heavy-first (R8 scheme).
// Block = 4 waves; wave wv owns q-rows j*128+wv*32..+32. 64-kv slab/round.
__global__ __launch_bounds__(256, 2) void k_attn(const short* __restrict__ Qs,
                                                 const short* __restrict__ Ks,
                                                 const short* __restrict__ Vt,
                                                 float* __restrict__ pws) {
    __shared__ __align__(16) char smem[2][16384];   // per buf: K 8KB | V 8KB

    int tid = threadIdx.x;
    int l = tid & 63, wv = tid >> 6;
    int q = l & 31, hi = l >> 5;

    // unit decode (R8): heavy j first; nseg(j) = (j+4)>>2
    int ub = blockIdx.x >> 2, bt = blockIdx.x & 3;
    int u = ub, j = 31, cs = 8;
    while (u >= cs) { u -= cs; --j; cs = (j + 4) >> 2; }
    int seg = u;
    int kb0 = seg << 9;
    int kend_t = min(j * 128 + 128, kb0 + 512);
    const int R = (kend_t - kb0 + 63) >> 6;
    const int q0 = j * 128 + wv * 32;
    const int mycend = q0 + 32;

    const short* Qb = Qs + (size_t)bt * SEQ * 64;
    const short* Kb = Ks + (size_t)bt * SEQ * 64;
    const short* Vb = Vt + (size_t)bt * 64 * SEQ;

    s16x8 qf[4];
#pragma unroll
    for (int d = 0; d < 4; d++)
        qf[d] = *(const s16x8*)(Qb + (size_t)(q0 + q) * 64 + d * 16 + hi * 8);

    const int row8 = l >> 3;
    const int scs  = (l & 7) ^ row8;       // pre-XORed source chunk

#define ASTAGE(kb, b) {                                                        \
        _Pragma("unroll")                                                      \
        for (int i = 0; i < 2; i++) {                                          \
            GLDS(Kb + (((size_t)((kb) + wv*16 + i*8 + row8)) << 6) + scs*8,    \
                 &smem[b][0] + (wv*16 + i*8)*128);                             \
            GLDS(Vb + (size_t)(wv*16 + i*8 + row8) * SEQ + (kb) + scs*8,       \
                 &smem[b][0] + 8192 + (wv*16 + i*8)*128); } }

    f32x16 o0 = {}, o1 = {};
    float m = -1e30f, ll = 0.f;
    const int qs7 = q & 7;

    ASTAGE(kb0, 0);
    if (R > 1) ASTAGE(kb0 + 64, 1);

    for (int r = 0; r < R; r++) {
        if (r == R - 1) asm volatile("s_waitcnt vmcnt(0)" ::: "memory");
        else            asm volatile("s_waitcnt vmcnt(4)" ::: "memory");
        __builtin_amdgcn_sched_barrier(0);
        __builtin_amdgcn_s_barrier();        // slab r ready for all waves

        // ---- LDS -> registers (the ONLY barrier-bracketed work) ----
        const char* kl = &smem[r & 1][0];
        const char* vl = kl + 8192;
        s16x8 kf[8], vf[8];
#pragma unroll
        for (int dd = 0; dd < 4; dd++) {
            int ch = ((2 * dd + hi) ^ qs7) << 4;
            kf[dd]     = *(const s16x8*)(kl + q * 128 + ch);
            kf[4 + dd] = *(const s16x8*)(kl + (32 + q) * 128 + ch);
            vf[dd]     = *(const s16x8*)(vl + q * 128 + ch);
            vf[4 + dd] = *(const s16x8*)(vl + (32 + q) * 128 + ch);
        }
        asm volatile("s_waitcnt lgkmcnt(0)" ::: "memory");  // reads retired
        __builtin_amdgcn_sched_barrier(0);
        __builtin_amdgcn_s_barrier();        // slab free for overwrite
        if (r + 2 < R) { if (r & 1) ASTAGE(kb0 + (r + 2) * 64, 1) else ASTAGE(kb0 + (r + 2) * 64, 0) }

        // ---- barrier-free compute from registers ----
        int k0 = kb0 + r * 64;
        if (k0 < mycend) {
            f32x16 sa = {}, sb = {};
            __builtin_amdgcn_s_setprio(1);
#pragma unroll
            for (int dd = 0; dd < 4; dd++) {
                sa = MFMA32(kf[dd],     qf[dd], sa);
                sb = MFMA32(kf[4 + dd], qf[dd], sb);
            }
            __builtin_amdgcn_s_setprio(0);
            if (k0 + 31 > q0) {
#pragma unroll
                for (int rr = 0; rr < 16; rr++) {
                    int kv = k0 + (rr & 3) + 8 * (rr >> 2) + 4 * hi;
                    if (kv > q0 + q) sa[rr] = -3.0e38f;
                }
            }
            if (k0 + 63 > q0) {
#pragma unroll
                for (int rr = 0; rr < 16; rr++) {
                    int kv = k0 + 32 + (rr & 3) + 8 * (rr >> 2) + 4 * hi;
                    if (kv > q0 + q) sb[rr] = -3.0e38f;
                }
            }
            SMTREE(sa, sb, m, ll, o0, o1);
            pfrag u0_, u1_, u2_, u3_;
            PACKPH(sa, sb, u0_, u1_, u2_, u3_);
            __builtin_amdgcn_s_setprio(1);
            o0 = MFMA32(vf[0], u0_.v, o0);
            o0 = MFMA32(vf[1], u1_.v, o0);
            o0 = MFMA32(vf[2], u2_.v, o0);
            o0 = MFMA32(vf[3], u3_.v, o0);
            o1 = MFMA32(vf[4], u0_.v, o1);
            o1 = MFMA32(vf[5], u1_.v, o1);
            o1 = MFMA32(vf[6], u2_.v, o1);
            o1 = MFMA32(vf[7], u3_.v, o1);
            __builtin_amdgcn_s_setprio(0);
        }
    }
#undef ASTAGE

    // ---- per-wave partial (O^T, M, L) -> ws ----
    float* p = pws + ((((size_t)(bt * 32 + j) * 4 + wv) * 8 + seg)) * 2112;
#pragma unroll
    for (int rr = 0; rr < 16; rr++) {
        int dv = (rr & 3) + 8 * (rr >> 2) + 4 * hi;
        p[dv * 32 + q]        = o0[rr];
        p[(dv + 32) * 32 + q] = o1[rr];
    }
    if (hi == 0) { p[2048 + q] = m; p[2080 + q] = ll; }
}

// ---------------------------------------------------------------------------
// Kernel 3: merge <=8 segment partials per (bt, j, wave-sub) -> fp32 out.
__global__ __launch_bounds__(256) void k_comb(const float* __restrict__ pws,
                                              float* __restrict__ out) {
    int b = blockIdx.x;                      // bt*128 + j*4 + w
    int w = b & 3, j = (b >> 2) & 31, bt = b >> 7;
    int nseg = (j + 4) >> 2;

    int tid = threadIdx.x;
    int q = tid >> 3, dv0 = (tid & 7) * 8;
    const float* base = pws + ((size_t)(bt * 32 + j) * 4 + w) * 8 * 2112;

    float ms[8], wsg[8];
    float M = -1e30f;
#pragma unroll
    for (int s = 0; s < 8; s++) {
        if (s < nseg) { ms[s] = base[s * 2112 + 2048 + q]; M = fmaxf(M, ms[s]); }
    }
    float L = 0.f;
#pragma unroll
    for (int s = 0; s < 8; s++) {
        if (s < nseg) {
            wsg[s] = __builtin_amdgcn_exp2f(ms[s] - M);
            L += wsg[s] * base[s * 2112 + 2080 + q];
        }
    }
    float inv = 1.0f / L;
    float res[8];
#pragma unroll
    for (int i = 0; i < 8; i++) res[i] = 0.f;
#pragma unroll
    for (int s = 0; s < 8; s++) {
        if (s < nseg) {
            const float* po = base + s * 2112;
#pragma unroll
            for (int i = 0; i < 8; i++) res[i] += wsg[s] * po[(dv0 + i) * 32 + q];
        }
    }
    float* op = out + ((size_t)bt * SEQ + j * 128 + w * 32 + q) * 64 + dv0;
    float4 f0 = {res[0] * inv, res[1] * inv, res[2] * inv, res[3] * inv};
    float4 f1 = {res[4] * inv, res[5] * inv, res[6] * inv, res[7] * inv};
    *(float4*)op = f0;
    *(float4*)(op + 4) = f1;
}

// ---------------------------------------------------------------------------
extern "C" void kernel_launch(void* const* d_in, const int* in_sizes, int n_in,
                              void* d_out, int out_size, void* d_ws, size_t ws_size,
                              hipStream_t stream) {
    const float* x  = (const float*)d_in[0];
    const float* Wq = (const float*)d_in[1];
    const float* Wk = (const float*)d_in[2];
    const float* Wv = (const float*)d_in[3];
    float* out = (float*)d_out;

    char* ws = (char*)d_ws;
    short* Wb = (short*)ws;                                   // 384 KB
    short* Qs = (short*)(ws + 393216);                        // 2 MB
    short* Ks = (short*)(ws + 393216 + 2097152);              // 2 MB
    short* Vt = (short*)(ws + 393216 + 2 * 2097152);          // 2 MB  [B][64][S]
    float* pP = (float*)(ws + 6684672);                       // partials ~34.6 MB

    k_convw<<<dim3(192), dim3(256), 0, stream>>>(Wq, Wk, Wv, Wb);
    k_proj <<<dim3(256), dim3(512), 0, stream>>>(x, Wb, Qs, Ks, Vt);
    k_attn <<<dim3(576), dim3(256), 0, stream>>>(Qs, Ks, Vt, pP);
    k_comb <<<dim3(512), dim3(256), 0, stream>>>(pP, out);
}